// Round 1
// baseline (1477.162 us; speedup 1.0000x reference)
//
#include <hip/hip_runtime.h>
#include <math.h>

#define BN_EPS 1e-5f

// ---------------------------------------------------------------------------
// conv1: x[b][0][128][128] -> h1[b][64][134][134], 3x3 pad=4, +bias, BN, ReLU
// ---------------------------------------------------------------------------
__global__ __launch_bounds__(256) void conv1_kernel(
    const float* __restrict__ x, const float* __restrict__ w,
    const float* __restrict__ bias, const float* __restrict__ g,
    const float* __restrict__ be, const float* __restrict__ m,
    const float* __restrict__ v, float* __restrict__ out, int b0)
{
    const int H1 = 134, W1 = 134;
    int b = blockIdx.z;
    int c = blockIdx.y;
    int sp = blockIdx.x * 256 + threadIdx.x;
    if (sp >= H1 * W1) return;
    int y = sp / W1, xx = sp - y * W1;

    float wv[9];
#pragma unroll
    for (int k = 0; k < 9; k++) wv[k] = w[c * 9 + k];

    const float* xin = x + (size_t)(b0 + b) * 128 * 128;
    float acc = 0.f;
#pragma unroll
    for (int ky = 0; ky < 3; ky++) {
        int iy = y - 4 + ky;
        if (iy < 0 || iy >= 128) continue;
#pragma unroll
        for (int kx = 0; kx < 3; kx++) {
            int ix = xx - 4 + kx;
            if (ix < 0 || ix >= 128) continue;
            acc = fmaf(xin[iy * 128 + ix], wv[ky * 3 + kx], acc);
        }
    }
    float inv = g[c] * rsqrtf(v[c] + BN_EPS);
    float val = (acc + bias[c]) * inv + (be[c] - m[c] * inv);
    out[(((size_t)b * 64 + c) * H1 + y) * W1 + xx] = fmaxf(val, 0.f);
}

// ---------------------------------------------------------------------------
// conv2/conv3: [Bc][IC][HIN][WIN] -> [Bc][32][HIN-2][WIN-2], 3x3 valid,
// +bias, BN, ReLU.  Block: 256 thr = 16x16 spatial x 32 oc tile;
// thread = 4 consecutive rows x 8 oc.
// ---------------------------------------------------------------------------
template <int IC, int HIN, int WIN>
__global__ __launch_bounds__(256) void conv3x3_bn_relu(
    const float* __restrict__ in, const float* __restrict__ w,
    const float* __restrict__ bias, const float* __restrict__ g,
    const float* __restrict__ be, const float* __restrict__ m,
    const float* __restrict__ v, float* __restrict__ out)
{
    constexpr int OC = 32;
    constexpr int HOUT = HIN - 2, WOUT = WIN - 2;
    constexpr int ICC = 8;

    __shared__ float sIn[ICC][18][18];
    __shared__ float sW[ICC][9][OC];   // [ic][k][oc]

    int t = threadIdx.x;
    int b = blockIdx.z;
    int x0 = blockIdx.x * 16, y0 = blockIdx.y * 16;
    int px  = t & 15;
    int rg  = (t >> 4) & 3;
    int ocg = t >> 6;          // 0..3 (one per wave)
    int py  = rg * 4;
    int ocb = ocg * 8;

    const float* inb = in + (size_t)b * IC * HIN * WIN;

    float acc[4][8];
#pragma unroll
    for (int pr = 0; pr < 4; pr++)
#pragma unroll
        for (int j = 0; j < 8; j++) acc[pr][j] = 0.f;

    for (int ic0 = 0; ic0 < IC; ic0 += ICC) {
        __syncthreads();
        // stage input patch (ICC x 18 x 18)
        for (int idx = t; idx < ICC * 18 * 18; idx += 256) {
            int ic = idx / 324; int rem = idx - ic * 324;
            int r = rem / 18, cc = rem - r * 18;
            int iy = y0 + r, ix = x0 + cc;
            float val = 0.f;
            if (iy < HIN && ix < WIN)
                val = inb[((size_t)(ic0 + ic) * HIN + iy) * WIN + ix];
            sIn[ic][r][cc] = val;
        }
        // stage weights (ICC x 9 x 32)
        for (int idx = t; idx < ICC * 9 * OC; idx += 256) {
            int ic = idx / (9 * OC); int rem = idx - ic * (9 * OC);
            int k = rem / OC; int oc = rem - k * OC;
            sW[ic][k][oc] = w[((size_t)oc * IC + ic0 + ic) * 9 + k];
        }
        __syncthreads();

#pragma unroll
        for (int ic = 0; ic < ICC; ic++) {
            float a[6][3];
#pragma unroll
            for (int r = 0; r < 6; r++)
#pragma unroll
                for (int c = 0; c < 3; c++)
                    a[r][c] = sIn[ic][py + r][px + c];
#pragma unroll
            for (int k = 0; k < 9; k++) {
                const int ky = k / 3, kx = k - ky * 3;
                const float4 w0 = *(const float4*)&sW[ic][k][ocb];
                const float4 w1 = *(const float4*)&sW[ic][k][ocb + 4];
#pragma unroll
                for (int pr = 0; pr < 4; pr++) {
                    float av = a[pr + ky][kx];
                    acc[pr][0] = fmaf(av, w0.x, acc[pr][0]);
                    acc[pr][1] = fmaf(av, w0.y, acc[pr][1]);
                    acc[pr][2] = fmaf(av, w0.z, acc[pr][2]);
                    acc[pr][3] = fmaf(av, w0.w, acc[pr][3]);
                    acc[pr][4] = fmaf(av, w1.x, acc[pr][4]);
                    acc[pr][5] = fmaf(av, w1.y, acc[pr][5]);
                    acc[pr][6] = fmaf(av, w1.z, acc[pr][6]);
                    acc[pr][7] = fmaf(av, w1.w, acc[pr][7]);
                }
            }
        }
    }

    // epilogue: fold bias+BN, ReLU, store
    float sc[8], sh[8];
#pragma unroll
    for (int j = 0; j < 8; j++) {
        int c = ocb + j;
        float inv = g[c] * rsqrtf(v[c] + BN_EPS);
        sc[j] = inv;
        sh[j] = bias[c] * inv + be[c] - m[c] * inv;
    }
    int ox = x0 + px;
    if (ox < WOUT) {
#pragma unroll
        for (int pr = 0; pr < 4; pr++) {
            int oy = y0 + py + pr;
            if (oy >= HOUT) continue;
#pragma unroll
            for (int j = 0; j < 8; j++) {
                float val = fmaxf(fmaf(acc[pr][j], sc[j], sh[j]), 0.f);
                out[(((size_t)b * OC + ocb + j) * HOUT + oy) * WOUT + ox] = val;
            }
        }
    }
}

// ---------------------------------------------------------------------------
// conv4: h3[b][32][130][130] -> heat_raw[b0+b][128][128] (+bias, no BN)
// ---------------------------------------------------------------------------
__global__ __launch_bounds__(256) void conv4_kernel(
    const float* __restrict__ in, const float* __restrict__ w,
    const float* __restrict__ bias, float* __restrict__ heat_raw, int b0)
{
    int b = blockIdx.z;
    int sp = blockIdx.x * 256 + threadIdx.x;   // 0..16383
    int y = sp >> 7, x = sp & 127;

    __shared__ float sw[288];
    for (int i = threadIdx.x; i < 288; i += 256) sw[i] = w[i];
    __syncthreads();

    const float* inb = in + (size_t)b * 32 * 130 * 130;
    float acc = bias[0];
#pragma unroll 4
    for (int ic = 0; ic < 32; ic++) {
        const float* p = inb + (size_t)ic * 130 * 130 + y * 130 + x;
#pragma unroll
        for (int ky = 0; ky < 3; ky++)
#pragma unroll
            for (int kx = 0; kx < 3; kx++)
                acc = fmaf(p[ky * 130 + kx], sw[ic * 9 + ky * 3 + kx], acc);
    }
    heat_raw[(size_t)(b0 + b) * 16384 + sp] = acc;
}

// ---------------------------------------------------------------------------
// nodes kernel: per image, per 8x8 grid cell: sigmoid, max/sum/sx/sy,
// rank-16 threshold, valid mask, centroid nodes, count.
// ---------------------------------------------------------------------------
__global__ __launch_bounds__(256) void nodes_kernel(
    const float* __restrict__ heat_raw, float* __restrict__ nodes,
    float* __restrict__ valid, float* __restrict__ counts)
{
    int b = blockIdx.x;
    int gsl = threadIdx.x;            // grid slot 0..255
    int yi = gsl >> 4, xj = gsl & 15;
    const float* hb = heat_raw + (size_t)b * 16384;

    float mx = -1e30f, s = 0.f, sx = 0.f, sy = 0.f;
#pragma unroll
    for (int a = 0; a < 8; a++) {
        int row = yi * 8 + a;
        float yr = (float)row * (1.0f / 127.0f);
#pragma unroll
        for (int c = 0; c < 8; c++) {
            int col = xj * 8 + c;
            float hv = hb[row * 128 + col];
            float hs = 1.0f / (1.0f + expf(-hv));
            mx = fmaxf(mx, hs);
            s += hs;
            sx += hs * ((float)col * (1.0f / 127.0f));
            sy += hs * yr;
        }
    }

    __shared__ float gv[256];
    gv[gsl] = mx;
    __syncthreads();

    int cgt = 0, ceq = 0;
    for (int j = 0; j < 256; j++) {
        float vj = gv[j];
        cgt += (vj > mx) ? 1 : 0;
        ceq += (vj == mx) ? 1 : 0;
    }
    __shared__ float kth;
    if (cgt <= 16 && 16 < cgt + ceq) kth = mx;   // rank-16 (desc) value; ties write same value
    __syncthreads();

    float thresh = fmaxf(kth, 0.9f);
    bool val = mx > thresh;
    nodes[((size_t)b * 256 + gsl) * 2 + 0] = val ? sx / s : 0.f;
    nodes[((size_t)b * 256 + gsl) * 2 + 1] = val ? sy / s : 0.f;
    valid[(size_t)b * 256 + gsl] = val ? 1.f : 0.f;

    unsigned long long ball = __ballot(val);
    __shared__ int wc[4];
    if ((gsl & 63) == 0) wc[gsl >> 6] = __popcll(ball);
    __syncthreads();
    if (gsl == 0) counts[b] = (float)(wc[0] + wc[1] + wc[2] + wc[3]);
}

// ---------------------------------------------------------------------------
extern "C" void kernel_launch(void* const* d_in, const int* in_sizes, int n_in,
                              void* d_out, int out_size, void* d_ws, size_t ws_size,
                              hipStream_t stream)
{
    const float* x   = (const float*)d_in[0];
    const float* w1  = (const float*)d_in[1];
    const float* b1  = (const float*)d_in[2];
    const float* g1  = (const float*)d_in[3];
    const float* be1 = (const float*)d_in[4];
    const float* m1  = (const float*)d_in[5];
    const float* v1  = (const float*)d_in[6];
    const float* w2  = (const float*)d_in[7];
    const float* b2  = (const float*)d_in[8];
    const float* g2  = (const float*)d_in[9];
    const float* be2 = (const float*)d_in[10];
    const float* m2  = (const float*)d_in[11];
    const float* v2  = (const float*)d_in[12];
    const float* w3  = (const float*)d_in[13];
    const float* b3  = (const float*)d_in[14];
    const float* g3  = (const float*)d_in[15];
    const float* be3 = (const float*)d_in[16];
    const float* m3  = (const float*)d_in[17];
    const float* v3  = (const float*)d_in[18];
    const float* w4  = (const float*)d_in[19];
    const float* b4  = (const float*)d_in[20];

    float* out = (float*)d_out;
    float* out_nodes = out;                       // [64][256][2]
    float* out_heat  = out + 32768;               // [64][128][128]
    float* out_valid = out + 32768 + 1048576;     // [64][256]
    float* out_count = out + 32768 + 1048576 + 16384; // [64]

    const size_t H1SZ = (size_t)64 * 134 * 134;   // 1,149,184 floats/img
    const size_t H2SZ = (size_t)32 * 132 * 132;   //   557,568 floats/img
    // h3 aliases h1's region (h1 dead after conv2 of the same chunk;
    // h3 per-image 540,800 floats < H1SZ)
    const size_t perImgBytes = (H1SZ + H2SZ) * sizeof(float);

    int Bc = 64;
    while (Bc > 1 && (size_t)Bc * perImgBytes > ws_size) Bc >>= 1;

    float* h1 = (float*)d_ws;
    float* h2 = h1 + (size_t)Bc * H1SZ;
    float* h3 = h1;   // alias

    for (int b0 = 0; b0 < 64; b0 += Bc) {
        dim3 gd1((134 * 134 + 255) / 256, 64, Bc);
        conv1_kernel<<<gd1, 256, 0, stream>>>(x, w1, b1, g1, be1, m1, v1, h1, b0);

        dim3 gd2(9, 9, Bc);
        conv3x3_bn_relu<64, 134, 134><<<gd2, 256, 0, stream>>>(
            h1, w2, b2, g2, be2, m2, v2, h2);
        conv3x3_bn_relu<32, 132, 132><<<gd2, 256, 0, stream>>>(
            h2, w3, b3, g3, be3, m3, v3, h3);

        dim3 gd4(64, 1, Bc);
        conv4_kernel<<<gd4, 256, 0, stream>>>(h3, w4, b4, out_heat, b0);
    }

    nodes_kernel<<<64, 256, 0, stream>>>(out_heat, out_nodes, out_valid, out_count);
}

// Round 2
// 367.575 us; speedup vs baseline: 4.0187x; 4.0187x over previous
//
#include <hip/hip_runtime.h>
#include <math.h>

#define BN_EPS 1e-5f

typedef _Float16 half8 __attribute__((ext_vector_type(8)));
typedef float f32x4 __attribute__((ext_vector_type(4)));

// ---------------------------------------------------------------------------
// scale/shift precompute: sc = g*rsqrt(v+eps); sh = bias*sc + be - m*sc
// layout in scsh: [sc1(64) sh1(64) sc2(32) sh2(32) sc3(32) sh3(32)]
// ---------------------------------------------------------------------------
__global__ __launch_bounds__(128) void scsh_kernel(
    const float* __restrict__ b1, const float* __restrict__ g1,
    const float* __restrict__ be1, const float* __restrict__ m1,
    const float* __restrict__ v1,
    const float* __restrict__ b2, const float* __restrict__ g2,
    const float* __restrict__ be2, const float* __restrict__ m2,
    const float* __restrict__ v2,
    const float* __restrict__ b3, const float* __restrict__ g3,
    const float* __restrict__ be3, const float* __restrict__ m3,
    const float* __restrict__ v3,
    float* __restrict__ scsh)
{
    int t = threadIdx.x;
    if (t < 64) {
        float inv = g1[t] * rsqrtf(v1[t] + BN_EPS);
        scsh[t] = inv;
        scsh[64 + t] = b1[t] * inv + be1[t] - m1[t] * inv;
    } else if (t < 96) {
        int c = t - 64;
        float inv = g2[c] * rsqrtf(v2[c] + BN_EPS);
        scsh[128 + c] = inv;
        scsh[160 + c] = b2[c] * inv + be2[c] - m2[c] * inv;
    } else {
        int c = t - 96;
        float inv = g3[c] * rsqrtf(v3[c] + BN_EPS);
        scsh[192 + c] = inv;
        scsh[224 + c] = b3[c] * inv + be3[c] - m3[c] * inv;
    }
}

// ---------------------------------------------------------------------------
// weight transform: wT[r][oc][ic] (fp16, ic contiguous) from w[oc][ic][3][3]
// wT2: 9*32*64 = 18432 elems; wT3: 9*32*32 = 9216 elems
// ---------------------------------------------------------------------------
__global__ __launch_bounds__(256) void wtrans_kernel(
    const float* __restrict__ w2, const float* __restrict__ w3,
    _Float16* __restrict__ wT2, _Float16* __restrict__ wT3)
{
    int t = blockIdx.x * 256 + threadIdx.x;
    if (t < 18432) {
        int r = t / 2048; int rem = t - r * 2048;
        int oc = rem >> 6; int ic = rem & 63;
        wT2[t] = (_Float16)w2[(oc * 64 + ic) * 9 + r];
    } else if (t < 27648) {
        int u = t - 18432;
        int r = u / 1024; int rem = u - r * 1024;
        int oc = rem >> 5; int ic = rem & 31;
        wT3[u] = (_Float16)w3[(oc * 32 + ic) * 9 + r];
    }
}

// ---------------------------------------------------------------------------
// conv1: x[b][128][128] fp32 -> h1[b][134][134][64] fp16 (channel-last)
// pad=4; BN+ReLU folded via sc1/sh1. Weights read via uniform (SGPR) loads.
// ---------------------------------------------------------------------------
__global__ __launch_bounds__(256) void conv1_kernel(
    const float* __restrict__ x, const float* __restrict__ w1,
    const float* __restrict__ scsh, _Float16* __restrict__ h1)
{
    int b = blockIdx.z;
    int sp = blockIdx.x * 256 + threadIdx.x;
    if (sp >= 134 * 134) return;
    int oy = sp / 134, ox = sp - oy * 134;

    const float* xb = x + (size_t)b * 16384;
    float a[9];
#pragma unroll
    for (int ky = 0; ky < 3; ky++) {
        int iy = oy - 4 + ky;
#pragma unroll
        for (int kx = 0; kx < 3; kx++) {
            int ix = ox - 4 + kx;
            a[ky * 3 + kx] = (iy >= 0 && iy < 128 && ix >= 0 && ix < 128)
                                 ? xb[iy * 128 + ix] : 0.f;
        }
    }

    _Float16* outp = h1 + ((size_t)b * 17956 + sp) * 64;
#pragma unroll
    for (int ocb = 0; ocb < 64; ocb += 8) {
        half8 hv;
#pragma unroll
        for (int j = 0; j < 8; j++) {
            int oc = ocb + j;
            float acc = 0.f;
#pragma unroll
            for (int k = 0; k < 9; k++) acc = fmaf(a[k], w1[oc * 9 + k], acc);
            float val = fmaxf(acc * scsh[oc] + scsh[64 + oc], 0.f);
            hv[j] = (_Float16)val;
        }
        *(half8*)(outp + ocb) = hv;
    }
}

// ---------------------------------------------------------------------------
// MFMA implicit-GEMM 3x3 conv (valid), channel-last fp16 in/out, OC=32.
// Per-tap decomposition: 9 GEMMs of K=ICALL, chunked by 32.
// Block: 256 thr = 4 waves; tile 16x16 pixels x 32 oc; wave = 4 rows.
// A = input pixels (M=16 x-offsets), B = weights (N=16 oc), D[pix][oc].
// ---------------------------------------------------------------------------
template <int ICALL, int HIN, int WIN>
__global__ __launch_bounds__(256) void conv3x3_mfma(
    const _Float16* __restrict__ in,   // [b][HIN][WIN][ICALL]
    const _Float16* __restrict__ wT,   // [9][32][ICALL]
    const float* __restrict__ sc,      // [32]
    const float* __restrict__ sh,      // [32]
    _Float16* __restrict__ out)        // [b][HOUT][WOUT][32]
{
    constexpr int HOUT = HIN - 2, WOUT = WIN - 2;
    constexpr int NCH = ICALL / 32;
    constexpr int PSTR = 40;  // halves per pixel slot: 32 + 8 pad (80B)

    __shared__ _Float16 sIn[18 * 18 * PSTR];

    const int t = threadIdx.x;
    const int lane = t & 63;
    const int w = t >> 6;       // wave 0..3 -> rows 4w..4w+3
    const int tl = lane & 15;
    const int g = lane >> 4;
    const int b = blockIdx.z;
    const int x0 = blockIdx.x * 16, y0 = blockIdx.y * 16;

    const _Float16* inb = in + (size_t)b * HIN * WIN * ICALL;

    f32x4 acc[4][2];
#pragma unroll
    for (int pf = 0; pf < 4; pf++)
#pragma unroll
        for (int of = 0; of < 2; of++) acc[pf][of] = (f32x4){0.f, 0.f, 0.f, 0.f};

    for (int ch = 0; ch < NCH; ch++) {
        // weight fragments for this ic-chunk: B[k=8g+j][n=tl] = W[oc][ic]
        half8 wf[9][2];
#pragma unroll
        for (int r = 0; r < 9; r++)
#pragma unroll
            for (int of = 0; of < 2; of++)
                wf[r][of] = *(const half8*)(wT +
                    ((size_t)(r * 32 + of * 16 + tl)) * ICALL + ch * 32 + g * 8);

        __syncthreads();
        // stage 18x18 input patch, 32 ic of this chunk, channel-last + pad
        for (int idx = t; idx < 18 * 18 * 4; idx += 256) {
            int px = idx >> 2;
            int sg = idx & 3;
            int py = px / 18, pxx = px - py * 18;
            int iy = y0 + py, ix = x0 + pxx;
            half8 v = (half8){0, 0, 0, 0, 0, 0, 0, 0};
            if (iy < HIN && ix < WIN)
                v = *(const half8*)(inb + ((size_t)iy * WIN + ix) * ICALL +
                                    ch * 32 + sg * 8);
            *(half8*)(&sIn[px * PSTR + sg * 8]) = v;
        }
        __syncthreads();

#pragma unroll
        for (int r = 0; r < 9; r++) {
            const int ky = r / 3, kx = r - ky * 3;
#pragma unroll
            for (int pf = 0; pf < 4; pf++) {
                const int yl = w * 4 + pf + ky;
                half8 af = *(const half8*)(
                    &sIn[(yl * 18 + tl + kx) * PSTR + g * 8]);
                acc[pf][0] = __builtin_amdgcn_mfma_f32_16x16x32_f16(
                    af, wf[r][0], acc[pf][0], 0, 0, 0);
                acc[pf][1] = __builtin_amdgcn_mfma_f32_16x16x32_f16(
                    af, wf[r][1], acc[pf][1], 0, 0, 0);
            }
        }
    }

    // epilogue: D row = pixel x-offset 4g+i, col = oc = of*16+tl
    const float sc0 = sc[tl], sc1v = sc[16 + tl];
    const float sh0 = sh[tl], sh1v = sh[16 + tl];
    _Float16* outb = out + (size_t)b * HOUT * WOUT * 32;
#pragma unroll
    for (int pf = 0; pf < 4; pf++) {
        int y = y0 + w * 4 + pf;
        if (y >= HOUT) continue;
#pragma unroll
        for (int i = 0; i < 4; i++) {
            int xc = x0 + 4 * g + i;
            if (xc >= WOUT) continue;
            _Float16* q = outb + ((size_t)y * WOUT + xc) * 32 + tl;
            q[0]  = (_Float16)fmaxf(acc[pf][0][i] * sc0 + sh0, 0.f);
            q[16] = (_Float16)fmaxf(acc[pf][1][i] * sc1v + sh1v, 0.f);
        }
    }
}

// ---------------------------------------------------------------------------
// conv4: h3[b][130][130][32] fp16 -> heat_raw[b0+b][128][128] fp32
// ---------------------------------------------------------------------------
__global__ __launch_bounds__(256) void conv4_kernel(
    const _Float16* __restrict__ h3, const float* __restrict__ w4,
    const float* __restrict__ b4, float* __restrict__ heat, int b0)
{
    int b = blockIdx.z;
    int sp = blockIdx.x * 256 + threadIdx.x;
    int y = sp >> 7, x = sp & 127;

    const _Float16* hb = h3 + (size_t)b * 130 * 130 * 32;
    float acc = b4[0];
#pragma unroll
    for (int r = 0; r < 9; r++) {
        const int ky = r / 3, kx = r - ky * 3;
        const _Float16* p = hb + ((size_t)(y + ky) * 130 + (x + kx)) * 32;
        half8 v0 = *(const half8*)(p);
        half8 v1 = *(const half8*)(p + 8);
        half8 v2 = *(const half8*)(p + 16);
        half8 v3 = *(const half8*)(p + 24);
#pragma unroll
        for (int j = 0; j < 8; j++) {
            acc = fmaf((float)v0[j], w4[(j) * 9 + r], acc);
            acc = fmaf((float)v1[j], w4[(8 + j) * 9 + r], acc);
            acc = fmaf((float)v2[j], w4[(16 + j) * 9 + r], acc);
            acc = fmaf((float)v3[j], w4[(24 + j) * 9 + r], acc);
        }
    }
    heat[(size_t)(b0 + b) * 16384 + sp] = acc;
}

// ---------------------------------------------------------------------------
// nodes kernel (unchanged from passing fp32 version)
// ---------------------------------------------------------------------------
__global__ __launch_bounds__(256) void nodes_kernel(
    const float* __restrict__ heat_raw, float* __restrict__ nodes,
    float* __restrict__ valid, float* __restrict__ counts)
{
    int b = blockIdx.x;
    int gsl = threadIdx.x;
    int yi = gsl >> 4, xj = gsl & 15;
    const float* hb = heat_raw + (size_t)b * 16384;

    float mx = -1e30f, s = 0.f, sx = 0.f, sy = 0.f;
#pragma unroll
    for (int a = 0; a < 8; a++) {
        int row = yi * 8 + a;
        float yr = (float)row * (1.0f / 127.0f);
#pragma unroll
        for (int c = 0; c < 8; c++) {
            int col = xj * 8 + c;
            float hv = hb[row * 128 + col];
            float hs = 1.0f / (1.0f + expf(-hv));
            mx = fmaxf(mx, hs);
            s += hs;
            sx += hs * ((float)col * (1.0f / 127.0f));
            sy += hs * yr;
        }
    }

    __shared__ float gv[256];
    gv[gsl] = mx;
    __syncthreads();

    int cgt = 0, ceq = 0;
    for (int j = 0; j < 256; j++) {
        float vj = gv[j];
        cgt += (vj > mx) ? 1 : 0;
        ceq += (vj == mx) ? 1 : 0;
    }
    __shared__ float kth;
    if (cgt <= 16 && 16 < cgt + ceq) kth = mx;
    __syncthreads();

    float thresh = fmaxf(kth, 0.9f);
    bool val = mx > thresh;
    nodes[((size_t)b * 256 + gsl) * 2 + 0] = val ? sx / s : 0.f;
    nodes[((size_t)b * 256 + gsl) * 2 + 1] = val ? sy / s : 0.f;
    valid[(size_t)b * 256 + gsl] = val ? 1.f : 0.f;

    unsigned long long ball = __ballot(val);
    __shared__ int wc[4];
    if ((gsl & 63) == 0) wc[gsl >> 6] = __popcll(ball);
    __syncthreads();
    if (gsl == 0) counts[b] = (float)(wc[0] + wc[1] + wc[2] + wc[3]);
}

// ---------------------------------------------------------------------------
extern "C" void kernel_launch(void* const* d_in, const int* in_sizes, int n_in,
                              void* d_out, int out_size, void* d_ws, size_t ws_size,
                              hipStream_t stream)
{
    const float* x   = (const float*)d_in[0];
    const float* w1  = (const float*)d_in[1];
    const float* b1  = (const float*)d_in[2];
    const float* g1  = (const float*)d_in[3];
    const float* be1 = (const float*)d_in[4];
    const float* m1  = (const float*)d_in[5];
    const float* v1  = (const float*)d_in[6];
    const float* w2  = (const float*)d_in[7];
    const float* b2  = (const float*)d_in[8];
    const float* g2  = (const float*)d_in[9];
    const float* be2 = (const float*)d_in[10];
    const float* m2  = (const float*)d_in[11];
    const float* v2  = (const float*)d_in[12];
    const float* w3  = (const float*)d_in[13];
    const float* b3  = (const float*)d_in[14];
    const float* g3  = (const float*)d_in[15];
    const float* be3 = (const float*)d_in[16];
    const float* m3  = (const float*)d_in[17];
    const float* v3  = (const float*)d_in[18];
    const float* w4  = (const float*)d_in[19];
    const float* b4  = (const float*)d_in[20];

    float* out = (float*)d_out;
    float* out_nodes = out;                           // [64][256][2]
    float* out_heat  = out + 32768;                   // [64][128][128]
    float* out_valid = out + 32768 + 1048576;         // [64][256]
    float* out_count = out + 32768 + 1048576 + 16384; // [64]

    // workspace layout
    char* ws = (char*)d_ws;
    _Float16* wT2  = (_Float16*)ws;                   // 18432 halves
    _Float16* wT3  = (_Float16*)(ws + 36864);         // 9216 halves
    float*    scsh = (float*)(ws + 55296);            // 256 floats
    const size_t WREGION = 65536;

    const size_t H1SZ = (size_t)17956 * 64;   // halves per image
    const size_t H2SZ = (size_t)17424 * 32;
    const size_t perImgBytes = (H1SZ + H2SZ) * sizeof(_Float16);

    int Bc = 64;
    while (Bc > 1 && WREGION + (size_t)Bc * perImgBytes > ws_size) Bc >>= 1;

    _Float16* h1 = (_Float16*)(ws + WREGION);
    _Float16* h2 = h1 + (size_t)Bc * H1SZ;
    _Float16* h3 = h1;  // alias: h1 dead after conv2; h3 (540800/img) < H1SZ

    scsh_kernel<<<1, 128, 0, stream>>>(b1, g1, be1, m1, v1,
                                       b2, g2, be2, m2, v2,
                                       b3, g3, be3, m3, v3, scsh);
    wtrans_kernel<<<108, 256, 0, stream>>>(w2, w3, wT2, wT3);

    for (int b0 = 0; b0 < 64; b0 += Bc) {
        dim3 gd1(71, 1, Bc);
        conv1_kernel<<<gd1, 256, 0, stream>>>(x + (size_t)b0 * 16384, w1, scsh, h1);

        dim3 gd2(9, 9, Bc);
        conv3x3_mfma<64, 134, 134><<<gd2, 256, 0, stream>>>(
            h1, wT2, scsh + 128, scsh + 160, h2);
        conv3x3_mfma<32, 132, 132><<<gd2, 256, 0, stream>>>(
            h2, wT3, scsh + 192, scsh + 224, h3);

        dim3 gd4(64, 1, Bc);
        conv4_kernel<<<gd4, 256, 0, stream>>>(h3, w4, b4, out_heat, b0);
    }

    nodes_kernel<<<64, 256, 0, stream>>>(out_heat, out_nodes, out_valid, out_count);
}